// Round 1
// baseline (146.256 us; speedup 1.0000x reference)
//
#include <hip/hip_runtime.h>
#include <cstddef>
#include <cstdint>

// SupConLoss fused kernel, f32 baseline.
//
// Math: with adc_ij = (x_i . x_j)/T, the reference's row-max M_i cancels exactly:
//   P@D2 row i      = D2_i - num_i / s_i,   num_i = sum_{j!=i} e^{-adc_ij} D2_j,
//                                           s_i   = sum_{j!=i} e^{-adc_ij}
//   log_prob_ij     = adc_ij - log(den_i),  den_i = sum_{j!=i} e^{adc_ij}
//   mlpp_i          = (a_i - b_i*log(den_i)) / (b_i + 1e-5),
//                     a_i = sum_j m_ij*adc_ij, b_i = sum_j m_ij, m = mask*offdiag
//   loss            = -mean_i mlpp_i        (T/BASE_T == 1)
// |adc| <= 1/0.07 so e^{+-adc} <= 1.6e6: f32-safe without the max.

namespace {
constexpr int   kN    = 4096;   // 2B
constexpr int   kB    = 2048;
constexpr int   kD    = 128;    // feature dim == C
constexpr float kInvT = 1.0f / 0.07f;
}

__device__ __forceinline__ const float* contrast_row(const float* feats, int i) {
    // contrast = concat(features[:,0], features[:,1]); features layout [B][2][128]
    return feats + (size_t)(i & (kB - 1)) * (2 * kD) + (size_t)(i >> 11) * kD;
}

// Kernel A: per 64-row tile x j-chunk: dot products, exps, per-row scalar partials,
// and num += W @ D2 partials. Deterministic partial buffers (no float atomics).
__global__ __launch_bounds__(256, 2)
void supcon_main(const float* __restrict__ feats,
                 const float* __restrict__ maskp,
                 const float* __restrict__ Dp,
                 float* __restrict__ num_part,   // [jchunks][4096][128]
                 float* __restrict__ s_part,     // [jchunks][4096]
                 float* __restrict__ d_part,
                 float* __restrict__ a_part,
                 float* __restrict__ b_part,
                 int tilesPerChunk)
{
    __shared__ float XIT[128 * 64];  // k-major anchor tile: XIT[k*64 + row]   32 KB
    __shared__ float SHB[64 * 128];  // union: XJT[k*64+j] (phase1) | D2J[j*128+c] (phase3) 32 KB
    __shared__ float Wb[64 * 64];    // w tile, col-swizzled by (row>>2)       16 KB

    const int t  = threadIdx.x;
    const int tc = t & 15;           // 0..15 -> cols
    const int tr = t >> 4;           // 0..15 -> rows
    const int I0 = blockIdx.x * 64;
    const int jcIdx = blockIdx.y;

    // ---- stage XIT (once per block), k-major ----
    {
        const int jj = t & 15;
        const int k0 = (t >> 4) * 8;
        #pragma unroll
        for (int rr = 0; rr < 4; ++rr) {
            const int r = jj + 16 * rr;
            const float* rp = contrast_row(feats, I0 + r);
            const float4 v0 = *(const float4*)(rp + k0);
            const float4 v1 = *(const float4*)(rp + k0 + 4);
            XIT[(k0 + 0) * 64 + r] = v0.x;
            XIT[(k0 + 1) * 64 + r] = v0.y;
            XIT[(k0 + 2) * 64 + r] = v0.z;
            XIT[(k0 + 3) * 64 + r] = v0.w;
            XIT[(k0 + 4) * 64 + r] = v1.x;
            XIT[(k0 + 5) * 64 + r] = v1.y;
            XIT[(k0 + 6) * 64 + r] = v1.z;
            XIT[(k0 + 7) * 64 + r] = v1.w;
        }
    }

    float spart[4] = {0.f, 0.f, 0.f, 0.f};
    float dpart[4] = {0.f, 0.f, 0.f, 0.f};
    float apart[4] = {0.f, 0.f, 0.f, 0.f};
    float bpart[4] = {0.f, 0.f, 0.f, 0.f};
    float numacc[4][8];
    #pragma unroll
    for (int r = 0; r < 4; ++r)
        #pragma unroll
        for (int c = 0; c < 8; ++c) numacc[r][c] = 0.f;

    for (int jt = 0; jt < tilesPerChunk; ++jt) {
        const int J0 = (jcIdx * tilesPerChunk + jt) * 64;

        __syncthreads();  // prev iter's phase 3 done with SHB/Wb (first iter: XIT fence)

        // ---- stage XJT into SHB (k-major) ----
        {
            const int jj = t & 15;
            const int k0 = (t >> 4) * 8;
            #pragma unroll
            for (int rr = 0; rr < 4; ++rr) {
                const int r = jj + 16 * rr;
                const float* rp = contrast_row(feats, J0 + r);
                const float4 v0 = *(const float4*)(rp + k0);
                const float4 v1 = *(const float4*)(rp + k0 + 4);
                SHB[(k0 + 0) * 64 + r] = v0.x;
                SHB[(k0 + 1) * 64 + r] = v0.y;
                SHB[(k0 + 2) * 64 + r] = v0.z;
                SHB[(k0 + 3) * 64 + r] = v0.w;
                SHB[(k0 + 4) * 64 + r] = v1.x;
                SHB[(k0 + 5) * 64 + r] = v1.y;
                SHB[(k0 + 6) * 64 + r] = v1.z;
                SHB[(k0 + 7) * 64 + r] = v1.w;
            }
        }
        __syncthreads();

        // ---- phase 1: 4x4 dot-product tile, outer-product over k ----
        float acc[4][4];
        #pragma unroll
        for (int r = 0; r < 4; ++r)
            #pragma unroll
            for (int c = 0; c < 4; ++c) acc[r][c] = 0.f;

        #pragma unroll 4
        for (int k = 0; k < 128; ++k) {
            const float4 av = *(const float4*)&XIT[k * 64 + tr * 4];
            const float4 bv = *(const float4*)&SHB[k * 64 + tc * 4];
            const float a_[4] = {av.x, av.y, av.z, av.w};
            const float b_[4] = {bv.x, bv.y, bv.z, bv.w};
            #pragma unroll
            for (int r = 0; r < 4; ++r)
                #pragma unroll
                for (int c = 0; c < 4; ++c)
                    acc[r][c] = fmaf(a_[r], b_[c], acc[r][c]);
        }

        // ---- phase 2: exps, scalar partials, stage W ----
        #pragma unroll
        for (int r = 0; r < 4; ++r) {
            const int gi  = I0 + tr * 4 + r;
            const int row = tr * 4 + r;
            const float4 mv = *(const float4*)(maskp + (size_t)gi * kN + J0 + tc * 4);
            const float mm[4] = {mv.x, mv.y, mv.z, mv.w};
            #pragma unroll
            for (int cj = 0; cj < 4; ++cj) {
                const int gj = J0 + tc * 4 + cj;
                const float adc = acc[r][cj] * kInvT;
                const bool nd = (gj != gi);
                const float w = nd ? __expf(-adc) : 0.f;
                const float p = nd ? __expf(adc) : 0.f;
                const float m = nd ? mm[cj] : 0.f;
                spart[r] += w;
                dpart[r] += p;
                apart[r] = fmaf(m, adc, apart[r]);
                bpart[r] += m;
                Wb[row * 64 + ((tc * 4 + cj + tr) & 63)] = w;  // col-swizzle by row>>2
            }
        }
        __syncthreads();  // Wb written; SHB reads complete

        // ---- stage D2J into SHB (row-major [j][c]) ----
        {
            const int c4 = t & 31;
            const int j0 = t >> 5;
            #pragma unroll
            for (int rr = 0; rr < 8; ++rr) {
                const int jj = j0 + rr * 8;
                const int gj = J0 + jj;
                const float4 dv = *(const float4*)(Dp + (size_t)(gj & (kB - 1)) * kD + c4 * 4);
                *(float4*)&SHB[jj * 128 + c4 * 4] = dv;
            }
        }
        __syncthreads();

        // ---- phase 3: numacc += W @ D2J ----
        #pragma unroll 2
        for (int jk = 0; jk < 64; ++jk) {
            const float4 b0 = *(const float4*)&SHB[jk * 128 + tc * 4];
            const float4 b1 = *(const float4*)&SHB[jk * 128 + 64 + tc * 4];
            #pragma unroll
            for (int r = 0; r < 4; ++r) {
                const float aw = Wb[(tr * 4 + r) * 64 + ((jk + tr) & 63)];
                numacc[r][0] = fmaf(aw, b0.x, numacc[r][0]);
                numacc[r][1] = fmaf(aw, b0.y, numacc[r][1]);
                numacc[r][2] = fmaf(aw, b0.z, numacc[r][2]);
                numacc[r][3] = fmaf(aw, b0.w, numacc[r][3]);
                numacc[r][4] = fmaf(aw, b1.x, numacc[r][4]);
                numacc[r][5] = fmaf(aw, b1.y, numacc[r][5]);
                numacc[r][6] = fmaf(aw, b1.z, numacc[r][6]);
                numacc[r][7] = fmaf(aw, b1.w, numacc[r][7]);
            }
        }
    }

    // ---- epilogue: reduce per-row scalars across the 16 tc lanes (same wave) ----
    const int chunkBase = jcIdx * kN;
    #pragma unroll
    for (int r = 0; r < 4; ++r) {
        float s = spart[r], d = dpart[r], a = apart[r], b = bpart[r];
        #pragma unroll
        for (int off = 8; off >= 1; off >>= 1) {
            s += __shfl_xor(s, off, 16);
            d += __shfl_xor(d, off, 16);
            a += __shfl_xor(a, off, 16);
            b += __shfl_xor(b, off, 16);
        }
        const int gi = I0 + tr * 4 + r;
        if (tc == 0) {
            s_part[chunkBase + gi] = s;
            d_part[chunkBase + gi] = d;
            a_part[chunkBase + gi] = a;
            b_part[chunkBase + gi] = b;
        }
    }
    // ---- write num partials ----
    #pragma unroll
    for (int r = 0; r < 4; ++r) {
        const int gi = I0 + tr * 4 + r;
        const size_t base = ((size_t)chunkBase + gi) * 128;
        float4 v0 = make_float4(numacc[r][0], numacc[r][1], numacc[r][2], numacc[r][3]);
        float4 v1 = make_float4(numacc[r][4], numacc[r][5], numacc[r][6], numacc[r][7]);
        *(float4*)&num_part[base + tc * 4]      = v0;
        *(float4*)&num_part[base + 64 + tc * 4] = v1;
    }
}

// Kernel B: per-row finish: sum chunk partials, D_hat = softmax(0.7*(D2-num/s)+0.3*L2),
// per-row mlpp. One wave per row.
__global__ __launch_bounds__(256)
void supcon_finish(const float* __restrict__ num_part,
                   const float* __restrict__ s_part,
                   const float* __restrict__ d_part,
                   const float* __restrict__ a_part,
                   const float* __restrict__ b_part,
                   const float* __restrict__ Dp,
                   const float* __restrict__ Lp,
                   float* __restrict__ out,
                   float* __restrict__ mlpp,
                   int jchunks)
{
    const int w    = threadIdx.x >> 6;
    const int lane = threadIdx.x & 63;
    const int row  = blockIdx.x * 4 + w;
    const int c0 = lane, c1 = lane + 64;

    float n0 = 0.f, n1 = 0.f, s = 0.f, den = 0.f, a = 0.f, b = 0.f;
    for (int ch = 0; ch < jchunks; ++ch) {
        const size_t base = ((size_t)ch * kN + row) * 128;
        n0 += num_part[base + c0];
        n1 += num_part[base + c1];
        const int sb = ch * kN + row;
        s   += s_part[sb];
        den += d_part[sb];
        a   += a_part[sb];
        b   += b_part[sb];
    }
    const float* d2 = Dp + (size_t)(row & (kB - 1)) * kD;
    const float* l2 = Lp + (size_t)(row & (kB - 1)) * kD;
    const float inv_s = 1.0f / s;
    float z0 = 0.7f * (d2[c0] - n0 * inv_s) + 0.3f * l2[c0];
    float z1 = 0.7f * (d2[c1] - n1 * inv_s) + 0.3f * l2[c1];

    float mx = fmaxf(z0, z1);
    #pragma unroll
    for (int off = 32; off >= 1; off >>= 1) mx = fmaxf(mx, __shfl_xor(mx, off, 64));
    const float e0 = __expf(z0 - mx);
    const float e1 = __expf(z1 - mx);
    float sm = e0 + e1;
    #pragma unroll
    for (int off = 32; off >= 1; off >>= 1) sm += __shfl_xor(sm, off, 64);
    const float inv = 1.0f / sm;

    out[1 + (size_t)row * kD + c0] = e0 * inv;
    out[1 + (size_t)row * kD + c1] = e1 * inv;

    if (lane == 0)
        mlpp[row] = (a - b * __logf(den)) / (b + 1e-5f);
}

// Kernel C: loss = -mean(mlpp)
__global__ __launch_bounds__(256)
void supcon_loss(const float* __restrict__ mlpp, float* __restrict__ out)
{
    __shared__ float red[4];
    const int t = threadIdx.x;
    float v = 0.f;
    for (int i = t; i < kN; i += 256) v += mlpp[i];
    #pragma unroll
    for (int off = 32; off >= 1; off >>= 1) v += __shfl_xor(v, off, 64);
    if ((t & 63) == 0) red[t >> 6] = v;
    __syncthreads();
    if (t == 0)
        out[0] = -(red[0] + red[1] + red[2] + red[3]) * (1.0f / (float)kN);
}

extern "C" void kernel_launch(void* const* d_in, const int* in_sizes, int n_in,
                              void* d_out, int out_size, void* d_ws, size_t ws_size,
                              hipStream_t stream) {
    const float* feats = (const float*)d_in[0];  // [2048][2][128]
    const float* maskp = (const float*)d_in[1];  // [4096][4096]
    const float* Dp    = (const float*)d_in[2];  // [2048][128]
    const float* Lp    = (const float*)d_in[3];  // [2048][128]
    float* out = (float*)d_out;                  // [0]=loss, [1..]=D_hat [4096][128]

    int jchunks = 8;
    auto need = [](int jc) -> size_t {
        return (size_t)jc * kN * kD * 4      // num partials
             + (size_t)jc * kN * 4 * 4       // s,d,a,b partials
             + (size_t)kN * 4;               // mlpp
    };
    while (jchunks > 1 && need(jchunks) > ws_size) jchunks >>= 1;

    float* num_part = (float*)d_ws;
    float* s_part = num_part + (size_t)jchunks * kN * kD;
    float* d_part = s_part + (size_t)jchunks * kN;
    float* a_part = d_part + (size_t)jchunks * kN;
    float* b_part = a_part + (size_t)jchunks * kN;
    float* mlpp   = b_part + (size_t)jchunks * kN;

    const int tilesPerChunk = (kN / 64) / jchunks;

    supcon_main<<<dim3(kN / 64, jchunks), 256, 0, stream>>>(
        feats, maskp, Dp, num_part, s_part, d_part, a_part, b_part, tilesPerChunk);
    supcon_finish<<<kN / 4, 256, 0, stream>>>(
        num_part, s_part, d_part, a_part, b_part, Dp, Lp, out, mlpp, jchunks);
    supcon_loss<<<1, 256, 0, stream>>>(mlpp, out);
}

// Round 2
// 65.570 us; speedup vs baseline: 2.2305x; 2.2305x over previous
//
#include <hip/hip_runtime.h>
#include <cstddef>
#include <cstdint>

// SupConLoss fused, MFMA version.
//
// Math (row-max cancels exactly, see prior round):
//   num_i = sum_{j!=i} e^{-adc_ij} D2_j, s_i = sum_{j!=i} e^{-adc_ij}
//   den_i = sum_{j!=i} e^{+adc_ij},      a_i = sum m_ij adc_ij, b_i = sum m_ij
//   D_hat = softmax(0.7*(D2 - num/s) + 0.3*L2); loss = -mean((a - b*log den)/(b+1e-5))
// mask[i][j] = mask[i&2047][j&2047] (lab2 period 2048) -> only 16MB quadrant read.
// QK^T and PV both on mfma_f32_16x16x32_bf16; LDS tiles slot-XOR swizzled.

namespace {
constexpr int   kN     = 4096;
constexpr int   kB     = 2048;
constexpr int   kD     = 128;
constexpr float kInvT  = 1.0f / 0.07f;
constexpr int   ITILE  = 64;
constexpr int   JTILE  = 64;
constexpr int   NCHUNK = 8;
constexpr int   JT_PER = (kN / NCHUNK) / JTILE;  // 8
}

typedef __attribute__((ext_vector_type(8))) short bf16x8;
typedef __attribute__((ext_vector_type(4))) float f32x4;

__device__ __forceinline__ const float* contrast_row(const float* feats, int i) {
    // contrast = concat(features[:,0], features[:,1]); features [2048][2][128]
    return feats + (size_t)(i & (kB - 1)) * (2 * kD) + (size_t)(i >> 11) * kD;
}
__device__ __forceinline__ ushort f2bf(float x) {  // RNE f32->bf16 (finite inputs)
    union { float f; uint u; } v; v.f = x;
    return (ushort)((v.u + 0x7FFFu + ((v.u >> 16) & 1u)) >> 16);
}

__global__ __launch_bounds__(256, 2)
void supcon_mfma(const float* __restrict__ feats,
                 const float* __restrict__ maskp,
                 const float* __restrict__ Dp,
                 float* __restrict__ num_part,   // [8][4096][128]
                 float* __restrict__ s_part,     // [8][4096]
                 float* __restrict__ d_part,
                 float* __restrict__ a_part,
                 float* __restrict__ b_part)
{
    __shared__ ushort XI[ITILE * 128];     // [i][k] bf16, swizzled   16 KB
    __shared__ ushort XJ[JTILE * 128];     // [j][k] bf16, swizzled   16 KB
    __shared__ ushort Wt[ITILE * JTILE];   // [i][j] bf16, swizzled    8 KB
    __shared__ ushort DT[kD * JTILE];      // [C][j] bf16, swizzled   16 KB
    __shared__ float  sred[4][2][ITILE];   //                          2 KB

    const int t    = threadIdx.x;
    const int lane = t & 63;
    const int w    = t >> 6;
    const int l15  = lane & 15;
    const int lg   = lane >> 4;            // 0..3
    const int wqi  = w >> 1;               // i-half (QK cols / PV rows)
    const int wqj  = w & 1;                // j-half (QK rows) / C-half (PV cols)
    const int I0   = blockIdx.x * ITILE;
    const int chunk = blockIdx.y;
    const int Jbase = chunk * (kN / NCHUNK);

    // ---- stage XI (once) ----
    {
        const int r = t & 63, k0 = (t >> 6) * 32;
        const float* rp = contrast_row(feats, I0 + r) + k0;
        #pragma unroll
        for (int q = 0; q < 4; ++q) {
            const float4 v0 = *(const float4*)(rp + q * 8);
            const float4 v1 = *(const float4*)(rp + q * 8 + 4);
            uint4 u;
            u.x = (uint)f2bf(v0.x) | ((uint)f2bf(v0.y) << 16);
            u.y = (uint)f2bf(v0.z) | ((uint)f2bf(v0.w) << 16);
            u.z = (uint)f2bf(v1.x) | ((uint)f2bf(v1.y) << 16);
            u.w = (uint)f2bf(v1.z) | ((uint)f2bf(v1.w) << 16);
            const int k = k0 + q * 8;
            *(uint4*)&XI[r * 128 + (k ^ ((r & 7) << 3))] = u;
        }
    }
    __syncthreads();

    // ---- preload XI as B-fragments (col=i=l15, k consecutive) ----
    bf16x8 bI[2][4];
    #pragma unroll
    for (int n = 0; n < 2; ++n) {
        const int row = wqi * 32 + n * 16 + l15;
        #pragma unroll
        for (int ks = 0; ks < 4; ++ks) {
            const int k = ks * 32 + lg * 8;
            bI[n][ks] = *(const bf16x8*)&XI[row * 128 + (k ^ ((row & 7) << 3))];
        }
    }

    f32x4 numacc[2][4];
    #pragma unroll
    for (int m = 0; m < 2; ++m)
        #pragma unroll
        for (int n = 0; n < 4; ++n)
            numacc[m][n] = (f32x4){0.f, 0.f, 0.f, 0.f};
    float s_acc[2] = {0.f, 0.f}, d_acc[2] = {0.f, 0.f};
    float a_acc[2] = {0.f, 0.f}, b_acc[2] = {0.f, 0.f};

    for (int jt = 0; jt < JT_PER; ++jt) {
        const int J0 = Jbase + jt * JTILE;
        if (jt) __syncthreads();  // prev PV done with Wt/DT; prev QK done with XJ

        // ---- stage XJ ----
        {
            const int r = t & 63, k0 = (t >> 6) * 32;
            const float* rp = contrast_row(feats, J0 + r) + k0;
            #pragma unroll
            for (int q = 0; q < 4; ++q) {
                const float4 v0 = *(const float4*)(rp + q * 8);
                const float4 v1 = *(const float4*)(rp + q * 8 + 4);
                uint4 u;
                u.x = (uint)f2bf(v0.x) | ((uint)f2bf(v0.y) << 16);
                u.y = (uint)f2bf(v0.z) | ((uint)f2bf(v0.w) << 16);
                u.z = (uint)f2bf(v1.x) | ((uint)f2bf(v1.y) << 16);
                u.w = (uint)f2bf(v1.z) | ((uint)f2bf(v1.w) << 16);
                const int k = k0 + q * 8;
                *(uint4*)&XJ[r * 128 + (k ^ ((r & 7) << 3))] = u;
            }
        }
        // ---- stage DT = D2^T tile [C][j] (4j x 4C register transpose) ----
        #pragma unroll
        for (int it = 0; it < 2; ++it) {
            const int p  = t + 256 * it;
            const int jb = (p & 15) * 4;
            const int cb = (p >> 4) * 4;
            float4 dv[4];
            #pragma unroll
            for (int jj = 0; jj < 4; ++jj) {
                const int gj = (J0 + jb + jj) & (kB - 1);
                dv[jj] = *(const float4*)(Dp + (size_t)gj * kD + cb);
            }
            #pragma unroll
            for (int cc = 0; cc < 4; ++cc) {
                const float e0 = ((const float*)&dv[0])[cc];
                const float e1 = ((const float*)&dv[1])[cc];
                const float e2 = ((const float*)&dv[2])[cc];
                const float e3 = ((const float*)&dv[3])[cc];
                uint2 u;
                u.x = (uint)f2bf(e0) | ((uint)f2bf(e1) << 16);
                u.y = (uint)f2bf(e2) | ((uint)f2bf(e3) << 16);
                const int c = cb + cc;
                *(uint2*)&DT[c * 64 + (jb ^ ((c & 7) << 3))] = u;
            }
        }
        __syncthreads();

        // ---- QK^T (S^T frags: rows=j, cols=i) ----
        f32x4 acc[2][2];
        #pragma unroll
        for (int m = 0; m < 2; ++m)
            #pragma unroll
            for (int n = 0; n < 2; ++n)
                acc[m][n] = (f32x4){0.f, 0.f, 0.f, 0.f};
        #pragma unroll
        for (int ks = 0; ks < 4; ++ks) {
            bf16x8 aJ[2];
            #pragma unroll
            for (int m = 0; m < 2; ++m) {
                const int row = wqj * 32 + m * 16 + l15;
                const int k = ks * 32 + lg * 8;
                aJ[m] = *(const bf16x8*)&XJ[row * 128 + (k ^ ((row & 7) << 3))];
            }
            #pragma unroll
            for (int m = 0; m < 2; ++m)
                #pragma unroll
                for (int n = 0; n < 2; ++n)
                    acc[m][n] = __builtin_amdgcn_mfma_f32_16x16x32_bf16(
                        aJ[m], bI[n][ks], acc[m][n], 0, 0, 0);
        }

        // ---- phase 2: exps, scalars, W write ----
        #pragma unroll
        for (int m = 0; m < 2; ++m) {
            const int jl0 = wqj * 32 + m * 16 + lg * 4;  // local j of reg 0
            const int gj0 = J0 + jl0;
            #pragma unroll
            for (int n = 0; n < 2; ++n) {
                const int il = wqi * 32 + n * 16 + l15;
                const int gi = I0 + il;
                const float4 mv = *(const float4*)(
                    maskp + (size_t)(gi & (kB - 1)) * kN + (gj0 & (kB - 1)));
                ushort wp[4];
                #pragma unroll
                for (int r = 0; r < 4; ++r) {
                    const float adc = acc[m][n][r] * kInvT;
                    const bool nd = ((gj0 + r) != gi);
                    float wv = __expf(-adc);
                    float pv = __builtin_amdgcn_rcpf(wv);
                    float mm = ((const float*)&mv)[r];
                    if (!nd) { wv = 0.f; pv = 0.f; mm = 0.f; }
                    s_acc[n] += wv;
                    d_acc[n] += pv;
                    a_acc[n] = fmaf(mm, adc, a_acc[n]);
                    b_acc[n] += mm;
                    wp[r] = f2bf(wv);
                }
                uint2 u;
                u.x = (uint)wp[0] | ((uint)wp[1] << 16);
                u.y = (uint)wp[2] | ((uint)wp[3] << 16);
                *(uint2*)&Wt[il * 64 + (jl0 ^ ((il & 7) << 3))] = u;
            }
        }
        __syncthreads();  // Wt complete before PV reads

        // ---- PV: numacc += W @ D2 ----
        #pragma unroll
        for (int ks = 0; ks < 2; ++ks) {
            bf16x8 aW[2], bD[4];
            #pragma unroll
            for (int m = 0; m < 2; ++m) {
                const int row = wqi * 32 + m * 16 + l15;
                const int k = ks * 32 + lg * 8;
                aW[m] = *(const bf16x8*)&Wt[row * 64 + (k ^ ((row & 7) << 3))];
            }
            #pragma unroll
            for (int n = 0; n < 4; ++n) {
                const int c = wqj * 64 + n * 16 + l15;
                const int k = ks * 32 + lg * 8;
                bD[n] = *(const bf16x8*)&DT[c * 64 + (k ^ ((c & 7) << 3))];
            }
            #pragma unroll
            for (int m = 0; m < 2; ++m)
                #pragma unroll
                for (int n = 0; n < 4; ++n)
                    numacc[m][n] = __builtin_amdgcn_mfma_f32_16x16x32_bf16(
                        aW[m], bD[n], numacc[m][n], 0, 0, 0);
        }
    }

    // ---- per-row scalar reduction ----
    #pragma unroll
    for (int n = 0; n < 2; ++n) {
        float s = s_acc[n], d = d_acc[n], a = a_acc[n], b = b_acc[n];
        #pragma unroll
        for (int off = 16; off <= 32; off <<= 1) {
            s += __shfl_xor(s, off);
            d += __shfl_xor(d, off);
            a += __shfl_xor(a, off);
            b += __shfl_xor(b, off);
        }
        if (lane < 16) {
            const int il = wqi * 32 + n * 16 + lane;
            sred[0][wqj][il] = s;
            sred[1][wqj][il] = d;
            sred[2][wqj][il] = a;
            sred[3][wqj][il] = b;
        }
    }
    __syncthreads();
    if (t < 4 * ITILE) {
        const int aid = t >> 6, il = t & 63;
        const float v = sred[aid][0][il] + sred[aid][1][il];
        float* dst = (aid == 0) ? s_part : (aid == 1) ? d_part
                   : (aid == 2) ? a_part : b_part;
        dst[(size_t)chunk * kN + I0 + il] = v;
    }

    // ---- num partial writes ----
    #pragma unroll
    for (int m = 0; m < 2; ++m)
        #pragma unroll
        for (int n = 0; n < 4; ++n)
            #pragma unroll
            for (int r = 0; r < 4; ++r) {
                const int il = wqi * 32 + m * 16 + lg * 4 + r;
                const int c  = wqj * 64 + n * 16 + l15;
                num_part[((size_t)chunk * kN + I0 + il) * kD + c] = numacc[m][n][r];
            }
}

// Kernel B: per-row finish
__global__ __launch_bounds__(256)
void supcon_finish(const float* __restrict__ num_part,
                   const float* __restrict__ s_part,
                   const float* __restrict__ d_part,
                   const float* __restrict__ a_part,
                   const float* __restrict__ b_part,
                   const float* __restrict__ Dp,
                   const float* __restrict__ Lp,
                   float* __restrict__ out,
                   float* __restrict__ mlpp,
                   int jchunks)
{
    const int w    = threadIdx.x >> 6;
    const int lane = threadIdx.x & 63;
    const int row  = blockIdx.x * 4 + w;
    const int c0 = lane, c1 = lane + 64;

    float n0 = 0.f, n1 = 0.f, s = 0.f, den = 0.f, a = 0.f, b = 0.f;
    for (int ch = 0; ch < jchunks; ++ch) {
        const size_t base = ((size_t)ch * kN + row) * 128;
        n0 += num_part[base + c0];
        n1 += num_part[base + c1];
        const int sb = ch * kN + row;
        s   += s_part[sb];
        den += d_part[sb];
        a   += a_part[sb];
        b   += b_part[sb];
    }
    const float* d2 = Dp + (size_t)(row & (kB - 1)) * kD;
    const float* l2 = Lp + (size_t)(row & (kB - 1)) * kD;
    const float inv_s = 1.0f / s;
    float z0 = 0.7f * (d2[c0] - n0 * inv_s) + 0.3f * l2[c0];
    float z1 = 0.7f * (d2[c1] - n1 * inv_s) + 0.3f * l2[c1];

    float mx = fmaxf(z0, z1);
    #pragma unroll
    for (int off = 32; off >= 1; off >>= 1) mx = fmaxf(mx, __shfl_xor(mx, off, 64));
    const float e0 = __expf(z0 - mx);
    const float e1 = __expf(z1 - mx);
    float sm = e0 + e1;
    #pragma unroll
    for (int off = 32; off >= 1; off >>= 1) sm += __shfl_xor(sm, off, 64);
    const float inv = 1.0f / sm;

    out[1 + (size_t)row * kD + c0] = e0 * inv;
    out[1 + (size_t)row * kD + c1] = e1 * inv;

    if (lane == 0)
        mlpp[row] = (a - b * __logf(den)) / (b + 1e-5f);
}

// Kernel C: loss = -mean(mlpp)
__global__ __launch_bounds__(256)
void supcon_loss(const float* __restrict__ mlpp, float* __restrict__ out)
{
    __shared__ float red[4];
    const int t = threadIdx.x;
    float v = 0.f;
    for (int i = t; i < kN; i += 256) v += mlpp[i];
    #pragma unroll
    for (int off = 32; off >= 1; off >>= 1) v += __shfl_xor(v, off, 64);
    if ((t & 63) == 0) red[t >> 6] = v;
    __syncthreads();
    if (t == 0)
        out[0] = -(red[0] + red[1] + red[2] + red[3]) * (1.0f / (float)kN);
}

extern "C" void kernel_launch(void* const* d_in, const int* in_sizes, int n_in,
                              void* d_out, int out_size, void* d_ws, size_t ws_size,
                              hipStream_t stream) {
    const float* feats = (const float*)d_in[0];  // [2048][2][128]
    const float* maskp = (const float*)d_in[1];  // [4096][4096]
    const float* Dp    = (const float*)d_in[2];  // [2048][128]
    const float* Lp    = (const float*)d_in[3];  // [2048][128]
    float* out = (float*)d_out;                  // [0]=loss, [1..]=D_hat

    float* num_part = (float*)d_ws;                                  // 16.78 MB
    float* s_part = num_part + (size_t)NCHUNK * kN * kD;
    float* d_part = s_part + (size_t)NCHUNK * kN;
    float* a_part = d_part + (size_t)NCHUNK * kN;
    float* b_part = a_part + (size_t)NCHUNK * kN;
    float* mlpp   = b_part + (size_t)NCHUNK * kN;

    supcon_mfma<<<dim3(kN / ITILE, NCHUNK), 256, 0, stream>>>(
        feats, maskp, Dp, num_part, s_part, d_part, a_part, b_part);
    supcon_finish<<<kN / 4, 256, 0, stream>>>(
        num_part, s_part, d_part, a_part, b_part, Dp, Lp, out, mlpp, NCHUNK);
    supcon_loss<<<1, 256, 0, stream>>>(mlpp, out);
}

// Round 3
// 64.135 us; speedup vs baseline: 2.2804x; 1.0224x over previous
//
#include <hip/hip_runtime.h>
#include <cstddef>
#include <cstdint>

// SupConLoss fused, MFMA + direct-fragment-load version.
//
// Math (row-max cancels exactly):
//   num_i = sum_{j!=i} e^{-adc_ij} D2_j, s_i = sum_{j!=i} e^{-adc_ij}
//   den_i = sum_{j!=i} e^{+adc_ij},      a_i = sum m_ij adc_ij, b_i = sum m_ij
//   D_hat = softmax(0.7*(D2 - num/s) + 0.3*L2); loss = -mean((a - b*log den)/(b+1e-5))
// mask[i][j] = mask[i&2047][j&2047] (labels period 2048).
//
// Structure: prep kernel pre-converts contrast->bf16 (Xbf[4096][128]) and
// D2^T->bf16 (DTbf[128][4096]) so ALL MFMA fragments are direct coalesced
// 16B global loads (L2/L3-resident). Main kernel LDS = double-buffered Wt
// only -> ONE barrier per j-iteration. aJ/mask reg-prefetched 1 iter ahead.

namespace {
constexpr int   kN    = 4096;
constexpr int   kB    = 2048;
constexpr int   kD    = 128;
constexpr float kInvT = 1.0f / 0.07f;
}

typedef __attribute__((ext_vector_type(8))) short bf16x8;
typedef __attribute__((ext_vector_type(4))) float f32x4;

__device__ __forceinline__ ushort f2bf(float x) {  // RNE f32->bf16 (finite)
    union { float f; uint u; } v; v.f = x;
    return (ushort)((v.u + 0x7FFFu + ((v.u >> 16) & 1u)) >> 16);
}
__device__ __forceinline__ uint pack2(float a, float b) {
    return (uint)f2bf(a) | ((uint)f2bf(b) << 16);
}

// ---- prep: blocks [0,256): Xbf ; [256,320): DTbf (LDS transpose) ----
__global__ __launch_bounds__(256)
void supcon_prep(const float* __restrict__ feats, const float* __restrict__ Dp,
                 ushort* __restrict__ Xbf, ushort* __restrict__ DTbf)
{
    __shared__ float sh[64][129];
    const int b = blockIdx.x, t = threadIdx.x;
    if (b < 256) {
        const int gid = b * 256 + t;
        const int i = gid >> 4, k0 = (gid & 15) * 8;
        const float* rp = feats + (size_t)(i & (kB - 1)) * 256 + (i >> 11) * 128 + k0;
        const float4 v0 = *(const float4*)rp;
        const float4 v1 = *(const float4*)(rp + 4);
        uint4 u;
        u.x = pack2(v0.x, v0.y); u.y = pack2(v0.z, v0.w);
        u.z = pack2(v1.x, v1.y); u.w = pack2(v1.z, v1.w);
        *(uint4*)&Xbf[(size_t)i * kD + k0] = u;
    } else {
        const int J0 = (b - 256) * 64;
        const int r = t >> 2, c0 = (t & 3) * 32;
        const float* dp = Dp + (size_t)((J0 + r) & (kB - 1)) * kD + c0;
        #pragma unroll
        for (int q = 0; q < 8; ++q) {
            const float4 v = *(const float4*)(dp + q * 4);
            sh[r][c0 + q * 4 + 0] = v.x; sh[r][c0 + q * 4 + 1] = v.y;
            sh[r][c0 + q * 4 + 2] = v.z; sh[r][c0 + q * 4 + 3] = v.w;
        }
        __syncthreads();
        #pragma unroll
        for (int it = 0; it < 4; ++it) {
            const int wid = t + 256 * it;
            const int jg = wid & 7, c = wid >> 3;
            uint4 u;
            u.x = pack2(sh[jg * 8 + 0][c], sh[jg * 8 + 1][c]);
            u.y = pack2(sh[jg * 8 + 2][c], sh[jg * 8 + 3][c]);
            u.z = pack2(sh[jg * 8 + 4][c], sh[jg * 8 + 5][c]);
            u.w = pack2(sh[jg * 8 + 6][c], sh[jg * 8 + 7][c]);
            *(uint4*)&DTbf[(size_t)c * kN + J0 + jg * 8] = u;
        }
    }
}

__global__ __launch_bounds__(256, 2)
void supcon_mfma(const ushort* __restrict__ Xbf,
                 const ushort* __restrict__ DTbf,
                 const float* __restrict__ maskp,
                 float* __restrict__ num_part,   // [nchunk][4096][128]
                 float* __restrict__ s_part,
                 float* __restrict__ d_part,
                 float* __restrict__ a_part,
                 float* __restrict__ b_part,
                 int jt_per)
{
    __shared__ ushort Wt[2][64 * 64];   // double-buffered W tile  16 KB
    __shared__ float  sred[4][2][64];   //                          2 KB

    const int t    = threadIdx.x;
    const int lane = t & 63;
    const int l15  = lane & 15;
    const int lg   = lane >> 4;
    const int w    = t >> 6;
    const int wqi  = w >> 1;            // i-half
    const int wqj  = w & 1;             // j-half (QK) / C-half (PV)
    const int I0   = blockIdx.x * 64;
    const int chunk = blockIdx.y;
    const int Jbase = chunk * jt_per * 64;

    // bI: i-features as B-fragments (col=i=l15, k consecutive), direct global
    bf16x8 bI[2][4];
    #pragma unroll
    for (int n = 0; n < 2; ++n) {
        const size_t row = I0 + wqi * 32 + n * 16 + l15;
        #pragma unroll
        for (int ks = 0; ks < 4; ++ks)
            bI[n][ks] = *(const bf16x8*)&Xbf[row * kD + ks * 32 + lg * 8];
    }

    f32x4 numacc[2][4];
    #pragma unroll
    for (int m = 0; m < 2; ++m)
        #pragma unroll
        for (int n = 0; n < 4; ++n)
            numacc[m][n] = (f32x4){0.f, 0.f, 0.f, 0.f};
    float s_acc[2] = {0.f, 0.f}, d_acc[2] = {0.f, 0.f};
    float a_acc[2] = {0.f, 0.f}, b_acc[2] = {0.f, 0.f};

    // prefetch jt=0: aJ + mask
    bf16x8 aJn[2][4];
    float4 mvn[2][2];
    {
        #pragma unroll
        for (int m = 0; m < 2; ++m) {
            const size_t rowj = Jbase + wqj * 32 + m * 16 + l15;
            #pragma unroll
            for (int ks = 0; ks < 4; ++ks)
                aJn[m][ks] = *(const bf16x8*)&Xbf[rowj * kD + ks * 32 + lg * 8];
        }
        #pragma unroll
        for (int m = 0; m < 2; ++m) {
            const int gj0 = Jbase + wqj * 32 + m * 16 + lg * 4;
            #pragma unroll
            for (int n = 0; n < 2; ++n) {
                const int gi = I0 + wqi * 32 + n * 16 + l15;
                mvn[m][n] = *(const float4*)(maskp + (size_t)(gi & (kB - 1)) * kN + (gj0 & (kB - 1)));
            }
        }
    }

    int buf = 0;
    for (int jt = 0; jt < jt_per; ++jt) {
        const int J0 = Jbase + jt * 64;

        bf16x8 aJ[2][4];
        float4 mv[2][2];
        #pragma unroll
        for (int m = 0; m < 2; ++m) {
            #pragma unroll
            for (int ks = 0; ks < 4; ++ks) aJ[m][ks] = aJn[m][ks];
            mv[m][0] = mvn[m][0];
            mv[m][1] = mvn[m][1];
        }

        // bD for this iter (needed only after the barrier -> latency hidden)
        bf16x8 bD[4][2];
        #pragma unroll
        for (int n = 0; n < 4; ++n) {
            const size_t c = wqj * 64 + n * 16 + l15;
            #pragma unroll
            for (int ks = 0; ks < 2; ++ks)
                bD[n][ks] = *(const bf16x8*)&DTbf[c * kN + J0 + ks * 32 + lg * 8];
        }

        // prefetch next iter's aJ + mask
        if (jt + 1 < jt_per) {
            const int Jn = J0 + 64;
            #pragma unroll
            for (int m = 0; m < 2; ++m) {
                const size_t rowj = Jn + wqj * 32 + m * 16 + l15;
                #pragma unroll
                for (int ks = 0; ks < 4; ++ks)
                    aJn[m][ks] = *(const bf16x8*)&Xbf[rowj * kD + ks * 32 + lg * 8];
            }
            #pragma unroll
            for (int m = 0; m < 2; ++m) {
                const int gj0 = Jn + wqj * 32 + m * 16 + lg * 4;
                #pragma unroll
                for (int n = 0; n < 2; ++n) {
                    const int gi = I0 + wqi * 32 + n * 16 + l15;
                    mvn[m][n] = *(const float4*)(maskp + (size_t)(gi & (kB - 1)) * kN + (gj0 & (kB - 1)));
                }
            }
        }

        // ---- QK^T (S^T: rows=j, cols=i) ----
        f32x4 acc[2][2];
        #pragma unroll
        for (int m = 0; m < 2; ++m)
            #pragma unroll
            for (int n = 0; n < 2; ++n)
                acc[m][n] = (f32x4){0.f, 0.f, 0.f, 0.f};
        #pragma unroll
        for (int ks = 0; ks < 4; ++ks)
            #pragma unroll
            for (int m = 0; m < 2; ++m)
                #pragma unroll
                for (int n = 0; n < 2; ++n)
                    acc[m][n] = __builtin_amdgcn_mfma_f32_16x16x32_bf16(
                        aJ[m][ks], bI[n][ks], acc[m][n], 0, 0, 0);

        // ---- exps, scalars, W pack ----
        uint2 wpk[2][2];
        #pragma unroll
        for (int m = 0; m < 2; ++m) {
            const int jl0 = wqj * 32 + m * 16 + lg * 4;
            const int gj0 = J0 + jl0;
            #pragma unroll
            for (int n = 0; n < 2; ++n) {
                const int il = wqi * 32 + n * 16 + l15;
                const int gi = I0 + il;
                float wv4[4];
                #pragma unroll
                for (int r = 0; r < 4; ++r) {
                    const float adc = acc[m][n][r] * kInvT;
                    const bool nd = ((gj0 + r) != gi);
                    float wv = __expf(-adc);
                    float pv = __builtin_amdgcn_rcpf(wv);
                    float mm = ((const float*)&mv[m][n])[r];
                    if (!nd) { wv = 0.f; pv = 0.f; mm = 0.f; }
                    s_acc[n] += wv;
                    d_acc[n] += pv;
                    a_acc[n] = fmaf(mm, adc, a_acc[n]);
                    b_acc[n] += mm;
                    wv4[r] = wv;
                }
                wpk[m][n].x = pack2(wv4[0], wv4[1]);
                wpk[m][n].y = pack2(wv4[2], wv4[3]);
            }
        }
        // write Wt[buf] (swizzled), then ONE barrier, then PV reads it.
        #pragma unroll
        for (int m = 0; m < 2; ++m) {
            const int jl0 = wqj * 32 + m * 16 + lg * 4;
            #pragma unroll
            for (int n = 0; n < 2; ++n) {
                const int il = wqi * 32 + n * 16 + l15;
                *(uint2*)&Wt[buf][il * 64 + (jl0 ^ ((il & 7) << 3))] = wpk[m][n];
            }
        }
        __syncthreads();

        // ---- PV: numacc += W @ D2 ----
        #pragma unroll
        for (int ks = 0; ks < 2; ++ks) {
            bf16x8 aW[2];
            #pragma unroll
            for (int m = 0; m < 2; ++m) {
                const int row = wqi * 32 + m * 16 + l15;
                aW[m] = *(const bf16x8*)&Wt[buf][row * 64 + ((ks * 32 + lg * 8) ^ ((row & 7) << 3))];
            }
            #pragma unroll
            for (int m = 0; m < 2; ++m)
                #pragma unroll
                for (int n = 0; n < 4; ++n)
                    numacc[m][n] = __builtin_amdgcn_mfma_f32_16x16x32_bf16(
                        aW[m], bD[n][ks], numacc[m][n], 0, 0, 0);
        }
        buf ^= 1;
    }

    // ---- per-row scalar reduction (over lg groups, then over wqj halves) ----
    #pragma unroll
    for (int n = 0; n < 2; ++n) {
        float s = s_acc[n], d = d_acc[n], a = a_acc[n], b = b_acc[n];
        #pragma unroll
        for (int off = 16; off <= 32; off <<= 1) {
            s += __shfl_xor(s, off);
            d += __shfl_xor(d, off);
            a += __shfl_xor(a, off);
            b += __shfl_xor(b, off);
        }
        if (lane < 16) {
            const int il = wqi * 32 + n * 16 + lane;
            sred[0][wqj][il] = s;
            sred[1][wqj][il] = d;
            sred[2][wqj][il] = a;
            sred[3][wqj][il] = b;
        }
    }
    __syncthreads();
    {
        const int aid = t >> 6, il = t & 63;
        const float v = sred[aid][0][il] + sred[aid][1][il];
        float* dst = (aid == 0) ? s_part : (aid == 1) ? d_part
                   : (aid == 2) ? a_part : b_part;
        dst[(size_t)chunk * kN + I0 + il] = v;
    }

    // ---- num partial writes ----
    #pragma unroll
    for (int m = 0; m < 2; ++m)
        #pragma unroll
        for (int n = 0; n < 4; ++n)
            #pragma unroll
            for (int r = 0; r < 4; ++r) {
                const int il = wqi * 32 + m * 16 + lg * 4 + r;
                const int c  = wqj * 64 + n * 16 + l15;
                num_part[((size_t)chunk * kN + I0 + il) * kD + c] = numacc[m][n][r];
            }
}

// Kernel B: per-row finish
__global__ __launch_bounds__(256)
void supcon_finish(const float* __restrict__ num_part,
                   const float* __restrict__ s_part,
                   const float* __restrict__ d_part,
                   const float* __restrict__ a_part,
                   const float* __restrict__ b_part,
                   const float* __restrict__ Dp,
                   const float* __restrict__ Lp,
                   float* __restrict__ out,
                   float* __restrict__ mlpp,
                   int jchunks)
{
    const int w    = threadIdx.x >> 6;
    const int lane = threadIdx.x & 63;
    const int row  = blockIdx.x * 4 + w;
    const int c0 = lane, c1 = lane + 64;

    float n0 = 0.f, n1 = 0.f, s = 0.f, den = 0.f, a = 0.f, b = 0.f;
    for (int ch = 0; ch < jchunks; ++ch) {
        const size_t base = ((size_t)ch * kN + row) * 128;
        n0 += num_part[base + c0];
        n1 += num_part[base + c1];
        const int sb = ch * kN + row;
        s   += s_part[sb];
        den += d_part[sb];
        a   += a_part[sb];
        b   += b_part[sb];
    }
    const float* d2 = Dp + (size_t)(row & (kB - 1)) * kD;
    const float* l2 = Lp + (size_t)(row & (kB - 1)) * kD;
    const float inv_s = 1.0f / s;
    float z0 = 0.7f * (d2[c0] - n0 * inv_s) + 0.3f * l2[c0];
    float z1 = 0.7f * (d2[c1] - n1 * inv_s) + 0.3f * l2[c1];

    float mx = fmaxf(z0, z1);
    #pragma unroll
    for (int off = 32; off >= 1; off >>= 1) mx = fmaxf(mx, __shfl_xor(mx, off, 64));
    const float e0 = __expf(z0 - mx);
    const float e1 = __expf(z1 - mx);
    float sm = e0 + e1;
    #pragma unroll
    for (int off = 32; off >= 1; off >>= 1) sm += __shfl_xor(sm, off, 64);
    const float inv = 1.0f / sm;

    out[1 + (size_t)row * kD + c0] = e0 * inv;
    out[1 + (size_t)row * kD + c1] = e1 * inv;

    if (lane == 0)
        mlpp[row] = (a - b * __logf(den)) / (b + 1e-5f);
}

// Kernel C: loss = -mean(mlpp)
__global__ __launch_bounds__(256)
void supcon_loss(const float* __restrict__ mlpp, float* __restrict__ out)
{
    __shared__ float red[4];
    const int t = threadIdx.x;
    float v = 0.f;
    for (int i = t; i < kN; i += 256) v += mlpp[i];
    #pragma unroll
    for (int off = 32; off >= 1; off >>= 1) v += __shfl_xor(v, off, 64);
    if ((t & 63) == 0) red[t >> 6] = v;
    __syncthreads();
    if (t == 0)
        out[0] = -(red[0] + red[1] + red[2] + red[3]) * (1.0f / (float)kN);
}

extern "C" void kernel_launch(void* const* d_in, const int* in_sizes, int n_in,
                              void* d_out, int out_size, void* d_ws, size_t ws_size,
                              hipStream_t stream) {
    const float* feats = (const float*)d_in[0];  // [2048][2][128]
    const float* maskp = (const float*)d_in[1];  // [4096][4096]
    const float* Dp    = (const float*)d_in[2];  // [2048][128]
    const float* Lp    = (const float*)d_in[3];  // [2048][128]
    float* out = (float*)d_out;                  // [0]=loss, [1..]=D_hat

    ushort* Xbf  = (ushort*)d_ws;                         // 1 MB
    ushort* DTbf = Xbf + (size_t)kN * kD;                 // 1 MB
    float*  pbase = (float*)(DTbf + (size_t)kD * kN);

    auto need = [](int nc) -> size_t {
        return (size_t)kN * kD * 2 * 2                    // Xbf + DTbf
             + (size_t)nc * kN * kD * 4                   // num partials
             + (size_t)nc * kN * 4 * 4                    // s,d,a,b
             + (size_t)kN * 4;                            // mlpp
    };
    int nchunk = 8;
    while (nchunk > 1 && need(nchunk) > ws_size) nchunk >>= 1;

    float* num_part = pbase;
    float* s_part = num_part + (size_t)nchunk * kN * kD;
    float* d_part = s_part + (size_t)nchunk * kN;
    float* a_part = d_part + (size_t)nchunk * kN;
    float* b_part = a_part + (size_t)nchunk * kN;
    float* mlpp   = b_part + (size_t)nchunk * kN;

    const int jt_per = (kN / nchunk) / 64;

    supcon_prep<<<320, 256, 0, stream>>>(feats, Dp, Xbf, DTbf);
    supcon_mfma<<<dim3(kN / 64, nchunk), 256, 0, stream>>>(
        Xbf, DTbf, maskp, num_part, s_part, d_part, a_part, b_part, jt_per);
    supcon_finish<<<kN / 4, 256, 0, stream>>>(
        num_part, s_part, d_part, a_part, b_part, Dp, Lp, out, mlpp, nchunk);
    supcon_loss<<<1, 256, 0, stream>>>(mlpp, out);
}